// Round 19
// baseline (299.694 us; speedup 1.0000x reference)
//
#include <hip/hip_runtime.h>
#include <hip/hip_cooperative_groups.h>

// Lennard-Jones per-edge energy + segment-sum — single cooperative mega-kernel.
//
// R18 residual analysis: kernels sum to ~40us but total = 53.3 -> ~10-15us of
// launch gaps + inter-kernel drains. R19: one cooperative kernel:
//   Phase A: pack atom_types nibbles + zero cursor replicas    -> grid.sync
//   Phase B: grid-stride over edge chunks (typeT staged ONCE per block);
//            per chunk: front/scan/(off-path u64 reserve)/rank/copyout
//   Phase C: per-bucket accumulate -> out (acc aliases stage LDS)
// Fallback: R18 3-kernel pipeline if cooperative launch unavailable.
//
// Inputs: 0 sigma[16,16] 1 delta[16,16] 2 epsilon[16,16] (f32)
//         3 edge_len[E] 4 edge_cutoff[E] (f32)  5 edge_index[2,E] (int32)
//         6 atom_types[N] (int32)         Output: [N,1] f32.

namespace cg = cooperative_groups;

#define THREADS  512
#define EPT      8
#define EPB      (THREADS*EPT)   // 4096
#define STHREADS 256
#define BSHIFT   9
#define BSIZE    512
#define MAXB2    256
#define NMASK    511u
#define LDSWORDS 12544
#define NREP     8
#define NCU      256

__device__ __forceinline__ float lj_energy(float sig, float dlt, float eps,
                                           float len, float cut) {
    const float r  = sig / (len - dlt);
    const float r2 = r * r;
    const float x  = r2 * r2 * r2;               // (sig/(len-dlt))^6
    return 2.0f * eps * (x * x - x) * cut;
}

__device__ __forceinline__ void load_params(const float* __restrict__ sigma,
                                            const float* __restrict__ delta,
                                            const float* __restrict__ epsilon,
                                            float* s_sig, float* s_dlt, float* s_eps,
                                            int t) {
    if (t < 256) {
        const int i  = t >> 4;
        const int j  = t & 15;
        const int lo = min(i, j);
        const int hi = max(i, j);
        const int src = lo * 16 + hi;        // sym = triu(p)+triu(p,1).T
        s_sig[t] = fmaxf(sigma[src],   0.0f);
        s_dlt[t] = fmaxf(delta[src],   0.0f);
        s_eps[t] = fmaxf(epsilon[src], 0.0f);
    }
}

__device__ __forceinline__ uint32_t pack8(const int* at, int base, int n_nodes) {
    if (base + 8 <= n_nodes) {
        const int4 a = *reinterpret_cast<const int4*>(at + base);
        const int4 b = *reinterpret_cast<const int4*>(at + base + 4);
        return  (uint32_t)(a.x & 15)        | ((uint32_t)(a.y & 15) << 4)
             | ((uint32_t)(a.z & 15) << 8)  | ((uint32_t)(a.w & 15) << 12)
             | ((uint32_t)(b.x & 15) << 16) | ((uint32_t)(b.y & 15) << 20)
             | ((uint32_t)(b.z & 15) << 24) | ((uint32_t)(b.w & 15) << 28);
    }
    uint32_t v = 0;
    for (int k = 0; k < 8; ++k) {
        const int idx = base + k;
        const uint32_t tv = (idx < n_nodes) ? (uint32_t)(at[idx] & 15) : 0u;
        v |= tv << (4 * k);
    }
    return v;
}

// ================= cooperative mega-kernel ====================================
__global__ __launch_bounds__(THREADS) void lj_mega(
    const float* __restrict__ sigma,
    const float* __restrict__ delta,
    const float* __restrict__ epsilon,
    const float* __restrict__ edge_len,
    const float* __restrict__ edge_cutoff,
    const int*  __restrict__ edge_index,
    const int*  __restrict__ atom_types,
    uint32_t* __restrict__ packed,
    uint32_t* __restrict__ gcursor,          // [NREP][256]
    uint32_t* __restrict__ pairs,            // [nbucket][NREP][REGr]
    float* __restrict__ out,
    int n_edges, int n_nodes, int nbucket, int nchunk, int REGr)
{
    __shared__ float s_sig[256], s_dlt[256], s_eps[256];
    __shared__ __align__(16) uint32_t typeT[LDSWORDS];       // 50KB
    __shared__ uint32_t hist[MAXB2], cursor[MAXB2], lbase[MAXB2], gbase[MAXB2];
    __shared__ __align__(16) uint32_t stageBuf[EPB + EPB/4]; // 20KB: stage+stageb
    uint32_t*      stage  = stageBuf;
    unsigned char* stageb = reinterpret_cast<unsigned char*>(stageBuf + EPB);

    cg::grid_group grid = cg::this_grid();
    const int t      = threadIdx.x;
    const int nwords = (n_nodes + 7) >> 3;

    // ---- Phase A: pack nibble table + zero cursor replicas ----
    {
        const int gtid = blockIdx.x * THREADS + t;
        if (gtid < NREP * 256) gcursor[gtid] = 0u;
        for (int w = gtid; w < nwords; w += gridDim.x * THREADS)
            packed[w] = pack8(atom_types, w * 8, n_nodes);
    }
    load_params(sigma, delta, epsilon, s_sig, s_dlt, s_eps, t);
    __threadfence();
    grid.sync();

    // ---- stage typeT once per block ----
    {
        const int nw4 = nwords >> 2;
        const uint4* s4 = reinterpret_cast<const uint4*>(packed);
        uint4* d4 = reinterpret_cast<uint4*>(typeT);
        for (int i = t; i < nw4; i += THREADS) d4[i] = s4[i];
        for (int i = (nw4 << 2) + t; i < nwords; i += THREADS) typeT[i] = packed[i];
    }
    __syncthreads();

    #define TYPE_OF(idx) ((typeT[(idx) >> 3] >> (((idx) & 7) << 2)) & 15u)

    // ---- Phase B: grid-stride over edge chunks ----
    for (int chunk = blockIdx.x; chunk < nchunk; chunk += gridDim.x) {
        if (t < MAXB2) hist[t] = 0u;
        __syncthreads();

        const int rep8    = chunk & (NREP - 1);
        const int blkbase = chunk * EPB;
        const int nval    = min(EPB, n_edges - blkbase);

        uint32_t pk[EPT];
        int      bk[EPT];
        #pragma unroll
        for (int i = 0; i < EPT / 4; ++i) {
            const int g = blkbase + i * (THREADS * 4) + t * 4;
            if (g + 3 < n_edges) {
                const int4   ctr = *reinterpret_cast<const int4*>(edge_index + g);
                const int4   oth = *reinterpret_cast<const int4*>(edge_index + n_edges + g);
                const float4 len = *reinterpret_cast<const float4*>(edge_len + g);
                const float4 cut = *reinterpret_cast<const float4*>(edge_cutoff + g);
                const int   c[4] = {ctr.x, ctr.y, ctr.z, ctr.w};
                const int   o[4] = {oth.x, oth.y, oth.z, oth.w};
                const float L[4] = {len.x, len.y, len.z, len.w};
                const float C[4] = {cut.x, cut.y, cut.z, cut.w};
                #pragma unroll
                for (int k = 0; k < 4; ++k) {
                    const int fl = (int)((TYPE_OF(c[k]) << 4) | TYPE_OF(o[k]));
                    const float e = lj_energy(s_sig[fl], s_dlt[fl], s_eps[fl],
                                              L[k], C[k]);
                    pk[i*4+k] = (__float_as_uint(e) & ~NMASK) | (uint32_t)(c[k] & NMASK);
                    bk[i*4+k] = c[k] >> BSHIFT;
                    atomicAdd(&hist[bk[i*4+k]], 1u);
                }
            } else {
                #pragma unroll
                for (int k = 0; k < 4; ++k) {
                    const int e_idx = g + k;
                    if (e_idx < n_edges) {
                        const int ci = edge_index[e_idx];
                        const int oi = edge_index[n_edges + e_idx];
                        const int fl = (int)((TYPE_OF(ci) << 4) | TYPE_OF(oi));
                        const float e = lj_energy(s_sig[fl], s_dlt[fl], s_eps[fl],
                                                  edge_len[e_idx], edge_cutoff[e_idx]);
                        pk[i*4+k] = (__float_as_uint(e) & ~NMASK) | (uint32_t)(ci & NMASK);
                        bk[i*4+k] = ci >> BSHIFT;
                        atomicAdd(&hist[bk[i*4+k]], 1u);
                    } else {
                        bk[i*4+k] = -1;
                    }
                }
            }
        }
        __syncthreads();   // hist = final counts

        // waves 1-2: u64 region reserve from counts (off critical path)
        if (t >= 64 && t < 192) {
            const int p  = t - 64;
            const int b0 = 2 * p, b1 = 2 * p + 1;
            const uint32_t cnt0 = hist[b0];
            const uint32_t cnt1 = hist[b1];
            if ((cnt0 | cnt1) != 0u) {
                unsigned long long* g64 =
                    reinterpret_cast<unsigned long long*>(gcursor + rep8 * 256) + p;
                const unsigned long long add =
                    (unsigned long long)cnt0 | ((unsigned long long)cnt1 << 32);
                const unsigned long long old = atomicAdd(g64, add);
                gbase[b0] = (uint32_t)old;
                gbase[b1] = (uint32_t)(old >> 32);
            }
        }
        // wave 0: exclusive scan of counts -> lbase + cursor
        if (t < 64) {
            uint32_t v[4]; uint32_t s = 0;
            #pragma unroll
            for (int k = 0; k < 4; ++k) {
                const uint32_t tmp = hist[t * 4 + k];
                v[k] = s; s += tmp;
            }
            uint32_t inc = s;
            #pragma unroll
            for (int off = 1; off < 64; off <<= 1) {
                const uint32_t u = __shfl_up(inc, off, 64);
                if (t >= off) inc += u;
            }
            const uint32_t lane_excl = inc - s;
            #pragma unroll
            for (int k = 0; k < 4; ++k) {
                const uint32_t e = lane_excl + v[k];
                lbase[t * 4 + k]  = e;
                cursor[t * 4 + k] = e;
            }
        }
        __syncthreads();

        // rank-scatter into LDS stage (+ bucket id)
        #pragma unroll
        for (int j = 0; j < EPT; ++j) {
            if (bk[j] >= 0) {
                const uint32_t r = atomicAdd(&cursor[bk[j]], 1u);
                stage[r]  = pk[j];
                stageb[r] = (unsigned char)bk[j];
            }
        }
        __syncthreads();

        // linear full-occupancy copy-out
        for (int i = t; i < nval; i += THREADS) {
            const int b = (int)stageb[i];
            const uint32_t pos = gbase[b] + ((uint32_t)i - lbase[b]);
            if (pos < (uint32_t)REGr)
                pairs[((size_t)b * NREP + rep8) * REGr + pos] = stage[i];
        }
        __syncthreads();
    }

    __threadfence();
    grid.sync();

    // ---- Phase C: per-bucket accumulate -> out (acc aliases stage LDS) ----
    float (*acc)[BSIZE] = reinterpret_cast<float(*)[BSIZE]>(stageBuf);  // 16KB
    for (int b = blockIdx.x; b < nbucket; b += gridDim.x) {
        #pragma unroll
        for (int w = 0; w < NREP; ++w) acc[w][t] = 0.0f;
        __syncthreads();

        const int wave = t >> 6;
        const int lane = t & 63;
        const uint32_t cnt = min(gcursor[wave * 256 + b], (uint32_t)REGr);
        const uint32_t* seg = pairs + ((size_t)b * NREP + wave) * REGr;
        for (uint32_t i = lane; i < cnt; i += 64) {
            const uint32_t p = seg[i];
            atomicAdd(&acc[wave][p & NMASK], __uint_as_float(p & ~NMASK));
        }
        __syncthreads();

        const long long n = (long long)b * BSIZE + t;
        if (n < n_nodes) {
            float s = 0.0f;
            #pragma unroll
            for (int w = 0; w < NREP; ++w) s += acc[w][t];
            out[n] = s;
        }
        __syncthreads();
    }
}

// ================= fallback pipeline (R18) ====================================
__global__ __launch_bounds__(STHREADS) void pack_types_kernel(
    const int* __restrict__ at, uint32_t* __restrict__ packed,
    uint32_t* __restrict__ gcursor, int n_nodes)
{
    if (blockIdx.x < NREP)
        gcursor[blockIdx.x * 256 + threadIdx.x] = 0u;
    const int w = blockIdx.x * STHREADS + threadIdx.x;
    const int nwords = (n_nodes + 7) >> 3;
    if (w < nwords) packed[w] = pack8(at, w * 8, n_nodes);
}

__global__ __launch_bounds__(THREADS) void lj_fused(
    const float* __restrict__ sigma,
    const float* __restrict__ delta,
    const float* __restrict__ epsilon,
    const float* __restrict__ edge_len,
    const float* __restrict__ edge_cutoff,
    const int*  __restrict__ edge_index,
    const uint32_t* __restrict__ packedT,
    uint32_t* __restrict__ gcursor,
    uint32_t* __restrict__ pairs,
    int n_edges, int n_nodes, int nbucket, int REGr)
{
    __shared__ float s_sig[256], s_dlt[256], s_eps[256];
    __shared__ __align__(16) uint32_t typeT[LDSWORDS];
    __shared__ uint32_t hist[MAXB2], cursor[MAXB2], lbase[MAXB2], gbase[MAXB2];
    __shared__ uint32_t stage[EPB];
    __shared__ unsigned char stageb[EPB];

    const int t = threadIdx.x;
    load_params(sigma, delta, epsilon, s_sig, s_dlt, s_eps, t);
    if (t < MAXB2) hist[t] = 0u;

    const int nwords = (n_nodes + 7) >> 3;
    {
        const int nw4 = nwords >> 2;
        const uint4* s4 = reinterpret_cast<const uint4*>(packedT);
        uint4* d4 = reinterpret_cast<uint4*>(typeT);
        for (int i = t; i < nw4; i += THREADS) d4[i] = s4[i];
        for (int i = (nw4 << 2) + t; i < nwords; i += THREADS) typeT[i] = packedT[i];
    }
    __syncthreads();

    const int blk     = blockIdx.x;
    const int rep8    = blk & (NREP - 1);
    const int blkbase = blk * EPB;
    const int nval    = min(EPB, n_edges - blkbase);

    uint32_t pk[EPT];
    int      bk[EPT];
    #pragma unroll
    for (int i = 0; i < EPT / 4; ++i) {
        const int g = blkbase + i * (THREADS * 4) + t * 4;
        if (g + 3 < n_edges) {
            const int4   ctr = *reinterpret_cast<const int4*>(edge_index + g);
            const int4   oth = *reinterpret_cast<const int4*>(edge_index + n_edges + g);
            const float4 len = *reinterpret_cast<const float4*>(edge_len + g);
            const float4 cut = *reinterpret_cast<const float4*>(edge_cutoff + g);
            const int   c[4] = {ctr.x, ctr.y, ctr.z, ctr.w};
            const int   o[4] = {oth.x, oth.y, oth.z, oth.w};
            const float L[4] = {len.x, len.y, len.z, len.w};
            const float C[4] = {cut.x, cut.y, cut.z, cut.w};
            #pragma unroll
            for (int k = 0; k < 4; ++k) {
                const int fl = (int)((TYPE_OF(c[k]) << 4) | TYPE_OF(o[k]));
                const float e = lj_energy(s_sig[fl], s_dlt[fl], s_eps[fl], L[k], C[k]);
                pk[i*4+k] = (__float_as_uint(e) & ~NMASK) | (uint32_t)(c[k] & NMASK);
                bk[i*4+k] = c[k] >> BSHIFT;
                atomicAdd(&hist[bk[i*4+k]], 1u);
            }
        } else {
            #pragma unroll
            for (int k = 0; k < 4; ++k) {
                const int e_idx = g + k;
                if (e_idx < n_edges) {
                    const int ci = edge_index[e_idx];
                    const int oi = edge_index[n_edges + e_idx];
                    const int fl = (int)((TYPE_OF(ci) << 4) | TYPE_OF(oi));
                    const float e = lj_energy(s_sig[fl], s_dlt[fl], s_eps[fl],
                                              edge_len[e_idx], edge_cutoff[e_idx]);
                    pk[i*4+k] = (__float_as_uint(e) & ~NMASK) | (uint32_t)(ci & NMASK);
                    bk[i*4+k] = ci >> BSHIFT;
                    atomicAdd(&hist[bk[i*4+k]], 1u);
                } else {
                    bk[i*4+k] = -1;
                }
            }
        }
    }
    __syncthreads();

    if (t >= 64 && t < 192) {
        const int p  = t - 64;
        const int b0 = 2 * p, b1 = 2 * p + 1;
        const uint32_t cnt0 = hist[b0];
        const uint32_t cnt1 = hist[b1];
        if ((cnt0 | cnt1) != 0u) {
            unsigned long long* g64 =
                reinterpret_cast<unsigned long long*>(gcursor + rep8 * 256) + p;
            const unsigned long long add =
                (unsigned long long)cnt0 | ((unsigned long long)cnt1 << 32);
            const unsigned long long old = atomicAdd(g64, add);
            gbase[b0] = (uint32_t)old;
            gbase[b1] = (uint32_t)(old >> 32);
        }
    }
    if (t < 64) {
        uint32_t v[4]; uint32_t s = 0;
        #pragma unroll
        for (int k = 0; k < 4; ++k) {
            const uint32_t tmp = hist[t * 4 + k];
            v[k] = s; s += tmp;
        }
        uint32_t inc = s;
        #pragma unroll
        for (int off = 1; off < 64; off <<= 1) {
            const uint32_t u = __shfl_up(inc, off, 64);
            if (t >= off) inc += u;
        }
        const uint32_t lane_excl = inc - s;
        #pragma unroll
        for (int k = 0; k < 4; ++k) {
            const uint32_t e = lane_excl + v[k];
            lbase[t * 4 + k]  = e;
            cursor[t * 4 + k] = e;
        }
    }
    __syncthreads();

    #pragma unroll
    for (int j = 0; j < EPT; ++j) {
        if (bk[j] >= 0) {
            const uint32_t r = atomicAdd(&cursor[bk[j]], 1u);
            stage[r]  = pk[j];
            stageb[r] = (unsigned char)bk[j];
        }
    }
    __syncthreads();

    for (int i = t; i < nval; i += THREADS) {
        const int b = (int)stageb[i];
        const uint32_t pos = gbase[b] + ((uint32_t)i - lbase[b]);
        if (pos < (uint32_t)REGr)
            pairs[((size_t)b * NREP + rep8) * REGr + pos] = stage[i];
    }
}

__global__ __launch_bounds__(THREADS) void lj_accum_direct(
    const uint32_t* __restrict__ pairs,
    const uint32_t* __restrict__ gcursor,
    float* __restrict__ out,
    int REGr, int n_nodes)
{
    __shared__ float acc[NREP][BSIZE];
    const int t = threadIdx.x;
    const int b = blockIdx.x;

    #pragma unroll
    for (int w = 0; w < NREP; ++w) acc[w][t] = 0.0f;
    __syncthreads();

    const int wave = t >> 6;
    const int lane = t & 63;
    const uint32_t cnt = min(gcursor[wave * 256 + b], (uint32_t)REGr);
    const uint32_t* seg = pairs + ((size_t)b * NREP + wave) * REGr;
    for (uint32_t i = lane; i < cnt; i += 64) {
        const uint32_t p = seg[i];
        atomicAdd(&acc[wave][p & NMASK], __uint_as_float(p & ~NMASK));
    }
    __syncthreads();

    const long long n = (long long)b * BSIZE + t;
    if (n < n_nodes) {
        float s = 0.0f;
        #pragma unroll
        for (int w = 0; w < NREP; ++w) s += acc[w][t];
        out[n] = s;
    }
}

__global__ __launch_bounds__(STHREADS) void lj_scatter_direct(
    const float* __restrict__ sigma,
    const float* __restrict__ delta,
    const float* __restrict__ epsilon,
    const float* __restrict__ edge_len,
    const float* __restrict__ edge_cutoff,
    const int*  __restrict__ edge_index,
    const int*  __restrict__ atom_types,
    float* __restrict__ out,
    int n_edges)
{
    __shared__ float s_sig[256], s_dlt[256], s_eps[256];
    const int t = threadIdx.x;
    load_params(sigma, delta, epsilon, s_sig, s_dlt, s_eps, t);
    __syncthreads();

    const int base = (blockIdx.x * STHREADS + t) * 4;
    if (base >= n_edges) return;
    const int lim = min(base + 4, n_edges);
    for (int e = base; e < lim; ++e) {
        const int ci = edge_index[e];
        const int oi = edge_index[n_edges + e];
        const int fl = (atom_types[ci] << 4) | atom_types[oi];
        const float en = lj_energy(s_sig[fl], s_dlt[fl], s_eps[fl],
                                   edge_len[e], edge_cutoff[e]);
        atomicAdd(out + ci, en);
    }
}

static inline size_t align16(size_t x) { return (x + 15) & ~(size_t)15; }

extern "C" void kernel_launch(void* const* d_in, const int* in_sizes, int n_in,
                              void* d_out, int out_size, void* d_ws, size_t ws_size,
                              hipStream_t stream) {
    const float* sigma       = (const float*)d_in[0];
    const float* delta       = (const float*)d_in[1];
    const float* epsilon     = (const float*)d_in[2];
    const float* edge_len    = (const float*)d_in[3];
    const float* edge_cutoff = (const float*)d_in[4];
    const int*   edge_index  = (const int*)d_in[5];
    const int*   atom_types  = (const int*)d_in[6];
    float*       out         = (float*)d_out;

    const int n_edges = in_sizes[3];
    const int n_nodes = in_sizes[6];

    const int nchunk  = (n_edges + EPB - 1) / EPB;
    const int nbucket = (n_nodes + BSIZE - 1) / BSIZE;
    const int nwords  = (n_nodes + 7) >> 3;

    int REGr = 2 * (n_edges / (nbucket > 0 ? nbucket * NREP : NREP));
    REGr = ((REGr + 511) / 512) * 512;
    if (REGr < 1024) REGr = 1024;

    const size_t gcur_bytes   = align16((size_t)NREP * 256 * sizeof(uint32_t));
    const size_t packed_bytes = align16((size_t)nwords * sizeof(uint32_t));
    const size_t pairs_bytes  = align16((size_t)nbucket * NREP * REGr * sizeof(uint32_t));
    const size_t need = gcur_bytes + packed_bytes + pairs_bytes;

    if (nbucket <= MAXB2 && nwords <= LDSWORDS && ws_size >= need) {
        char* p = (char*)d_ws;
        uint32_t* gcursor = (uint32_t*)p;  p += gcur_bytes;
        uint32_t* packed  = (uint32_t*)p;  p += packed_bytes;
        uint32_t* pairs   = (uint32_t*)p;

        // try the cooperative mega-kernel
        int maxPerCU = 0;
        hipError_t qerr = hipOccupancyMaxActiveBlocksPerMultiprocessor(
            &maxPerCU, (const void*)lj_mega, THREADS, 0);
        int grid = (qerr == hipSuccess) ? maxPerCU * NCU : 0;
        if (grid > nchunk) grid = nchunk;

        bool coop_ok = false;
        if (grid >= NREP && grid >= 1) {
            void* args[] = {
                (void*)&sigma, (void*)&delta, (void*)&epsilon,
                (void*)&edge_len, (void*)&edge_cutoff, (void*)&edge_index,
                (void*)&atom_types, (void*)&packed, (void*)&gcursor,
                (void*)&pairs, (void*)&out,
                (void*)&n_edges, (void*)&n_nodes, (void*)&nbucket,
                (void*)&nchunk, (void*)&REGr
            };
            hipError_t lerr = hipLaunchCooperativeKernel(
                (const void*)lj_mega, dim3(grid), dim3(THREADS), args, 0, stream);
            coop_ok = (lerr == hipSuccess);
        }

        if (!coop_ok) {
            // fallback: R18 3-kernel pipeline
            const int pgrid = max((nwords + STHREADS - 1) / STHREADS, NREP);
            pack_types_kernel<<<pgrid, STHREADS, 0, stream>>>(
                atom_types, packed, gcursor, n_nodes);
            lj_fused<<<nchunk, THREADS, 0, stream>>>(
                sigma, delta, epsilon, edge_len, edge_cutoff,
                edge_index, packed, gcursor, pairs, n_edges, n_nodes, nbucket, REGr);
            lj_accum_direct<<<nbucket, THREADS, 0, stream>>>(
                pairs, gcursor, out, REGr, n_nodes);
        }
    } else {
        hipMemsetAsync(d_out, 0, (size_t)out_size * sizeof(float), stream);
        const int grid = (n_edges + STHREADS * 4 - 1) / (STHREADS * 4);
        lj_scatter_direct<<<grid, STHREADS, 0, stream>>>(
            sigma, delta, epsilon, edge_len, edge_cutoff,
            edge_index, atom_types, out, n_edges);
    }
}

// Round 20
// 53.746 us; speedup vs baseline: 5.5761x; 5.5761x over previous
//
#include <hip/hip_runtime.h>

// Lennard-Jones per-edge energy + segment-sum — fused binning, replicated cursors.
// R20 = exact revert to R18 (best measured: 53.3us). R19's cooperative mega-kernel
// regressed 5.6x (grid.sync spin + persistent blocks defeat TLP) — launch gaps are
// cheaper than device-wide software sync on 8-XCD gfx950.
//
// Pipeline: K0 pack nibbles+zero cursors -> K1 fused (stage 50KB typeT in LDS,
// energy+pack, LDS hist, wave-0 scan, off-path u64 region reserve by waves 1-2,
// rank-scatter, linear copy-out to per-(bucket,replica) regions) -> K2 accum.
//
// Inputs: 0 sigma[16,16] 1 delta[16,16] 2 epsilon[16,16] (f32)
//         3 edge_len[E] 4 edge_cutoff[E] (f32)  5 edge_index[2,E] (int32)
//         6 atom_types[N] (int32)         Output: [N,1] f32.

#define THREADS  512
#define EPT      8
#define EPB      (THREADS*EPT)   // 4096
#define STHREADS 256
#define BSHIFT   9
#define BSIZE    512
#define MAXB2    256
#define NMASK    511u
#define LDSWORDS 12544
#define NREP     8               // cursor/region replica sets

__device__ __forceinline__ float lj_energy(float sig, float dlt, float eps,
                                           float len, float cut) {
    const float r  = sig / (len - dlt);
    const float r2 = r * r;
    const float x  = r2 * r2 * r2;               // (sig/(len-dlt))^6
    return 2.0f * eps * (x * x - x) * cut;
}

__device__ __forceinline__ void load_params(const float* __restrict__ sigma,
                                            const float* __restrict__ delta,
                                            const float* __restrict__ epsilon,
                                            float* s_sig, float* s_dlt, float* s_eps,
                                            int t) {
    if (t < 256) {
        const int i  = t >> 4;
        const int j  = t & 15;
        const int lo = min(i, j);
        const int hi = max(i, j);
        const int src = lo * 16 + hi;        // sym = triu(p)+triu(p,1).T
        s_sig[t] = fmaxf(sigma[src],   0.0f);
        s_dlt[t] = fmaxf(delta[src],   0.0f);
        s_eps[t] = fmaxf(epsilon[src], 0.0f);
    }
}

// ---------------- K0: pack atom_types into nibbles + zero cursor replicas -----
__global__ __launch_bounds__(STHREADS) void pack_types_kernel(
    const int* __restrict__ at, uint32_t* __restrict__ packed,
    uint32_t* __restrict__ gcursor, int n_nodes)
{
    if (blockIdx.x < NREP)
        gcursor[blockIdx.x * 256 + threadIdx.x] = 0u;
    const int w = blockIdx.x * STHREADS + threadIdx.x;
    const int nwords = (n_nodes + 7) >> 3;
    if (w >= nwords) return;
    const int base = w * 8;
    uint32_t v = 0;
    if (base + 8 <= n_nodes) {
        const int4 a = *reinterpret_cast<const int4*>(at + base);
        const int4 b = *reinterpret_cast<const int4*>(at + base + 4);
        v =  (uint32_t)(a.x & 15)        | ((uint32_t)(a.y & 15) << 4)
          | ((uint32_t)(a.z & 15) << 8)  | ((uint32_t)(a.w & 15) << 12)
          | ((uint32_t)(b.x & 15) << 16) | ((uint32_t)(b.y & 15) << 20)
          | ((uint32_t)(b.z & 15) << 24) | ((uint32_t)(b.w & 15) << 28);
    } else {
        for (int k = 0; k < 8; ++k) {
            const int idx = base + k;
            const uint32_t tv = (idx < n_nodes) ? (uint32_t)(at[idx] & 15) : 0u;
            v |= tv << (4 * k);
        }
    }
    packed[w] = v;
}

// ---------------- K1: fused energy + LDS sort + replicated-region scatter -----
__global__ __launch_bounds__(THREADS) void lj_fused(
    const float* __restrict__ sigma,
    const float* __restrict__ delta,
    const float* __restrict__ epsilon,
    const float* __restrict__ edge_len,
    const float* __restrict__ edge_cutoff,
    const int*  __restrict__ edge_index,     // [2,E]
    const uint32_t* __restrict__ packedT,    // [(n+7)/8]
    uint32_t* __restrict__ gcursor,          // [NREP][256] cursors
    uint32_t* __restrict__ pairs,            // [nbucket][NREP][REGr]
    int n_edges, int n_nodes, int nbucket, int REGr)
{
    __shared__ float s_sig[256], s_dlt[256], s_eps[256];
    __shared__ __align__(16) uint32_t typeT[LDSWORDS];  // 50KB nibble table
    __shared__ uint32_t hist[MAXB2];          // counts (NOT overwritten)
    __shared__ uint32_t cursor[MAXB2];        // rank cursors
    __shared__ uint32_t lbase[MAXB2];         // local exclusive base
    __shared__ uint32_t gbase[MAXB2];         // reserved global base
    __shared__ uint32_t stage[EPB];           // 16KB sorted stage
    __shared__ unsigned char stageb[EPB];     // 4KB bucket id per slot

    const int t = threadIdx.x;
    load_params(sigma, delta, epsilon, s_sig, s_dlt, s_eps, t);
    if (t < MAXB2) hist[t] = 0u;

    // stage nibble table into LDS
    const int nwords = (n_nodes + 7) >> 3;
    {
        const int nw4 = nwords >> 2;
        const uint4* s4 = reinterpret_cast<const uint4*>(packedT);
        uint4* d4 = reinterpret_cast<uint4*>(typeT);
        for (int i = t; i < nw4; i += THREADS) d4[i] = s4[i];
        for (int i = (nw4 << 2) + t; i < nwords; i += THREADS) typeT[i] = packedT[i];
    }
    __syncthreads();

    #define TYPE_OF(idx) ((typeT[(idx) >> 3] >> (((idx) & 7) << 2)) & 15u)

    const int blk     = blockIdx.x;
    const int rep8    = blk & (NREP - 1);
    const int blkbase = blk * EPB;
    const int nval    = min(EPB, n_edges - blkbase);

    // 8 edges/thread: load + lookup + energy + pack + histogram
    uint32_t pk[EPT];
    int      bk[EPT];
    #pragma unroll
    for (int i = 0; i < EPT / 4; ++i) {
        const int g = blkbase + i * (THREADS * 4) + t * 4;
        if (g + 3 < n_edges) {
            const int4   ctr = *reinterpret_cast<const int4*>(edge_index + g);
            const int4   oth = *reinterpret_cast<const int4*>(edge_index + n_edges + g);
            const float4 len = *reinterpret_cast<const float4*>(edge_len + g);
            const float4 cut = *reinterpret_cast<const float4*>(edge_cutoff + g);
            const int   c[4] = {ctr.x, ctr.y, ctr.z, ctr.w};
            const int   o[4] = {oth.x, oth.y, oth.z, oth.w};
            const float L[4] = {len.x, len.y, len.z, len.w};
            const float C[4] = {cut.x, cut.y, cut.z, cut.w};
            #pragma unroll
            for (int k = 0; k < 4; ++k) {
                const int fl = (int)((TYPE_OF(c[k]) << 4) | TYPE_OF(o[k]));
                const float e = lj_energy(s_sig[fl], s_dlt[fl], s_eps[fl], L[k], C[k]);
                pk[i*4+k] = (__float_as_uint(e) & ~NMASK) | (uint32_t)(c[k] & NMASK);
                bk[i*4+k] = c[k] >> BSHIFT;
                atomicAdd(&hist[bk[i*4+k]], 1u);
            }
        } else {
            #pragma unroll
            for (int k = 0; k < 4; ++k) {
                const int e_idx = g + k;
                if (e_idx < n_edges) {
                    const int ci = edge_index[e_idx];
                    const int oi = edge_index[n_edges + e_idx];
                    const int fl = (int)((TYPE_OF(ci) << 4) | TYPE_OF(oi));
                    const float e = lj_energy(s_sig[fl], s_dlt[fl], s_eps[fl],
                                              edge_len[e_idx], edge_cutoff[e_idx]);
                    pk[i*4+k] = (__float_as_uint(e) & ~NMASK) | (uint32_t)(ci & NMASK);
                    bk[i*4+k] = ci >> BSHIFT;
                    atomicAdd(&hist[bk[i*4+k]], 1u);
                } else {
                    bk[i*4+k] = -1;
                }
            }
        }
    }
    __syncthreads();   // hist = final counts

    // waves 1-2: reserve region slots from COUNTS (concurrent with wave-0 scan;
    // hist is read-only from here on, so no race)
    if (t >= 64 && t < 192) {
        const int p  = t - 64;               // pair index 0..127
        const int b0 = 2 * p, b1 = 2 * p + 1;
        const uint32_t cnt0 = hist[b0];
        const uint32_t cnt1 = hist[b1];
        if ((cnt0 | cnt1) != 0u) {
            unsigned long long* g64 =
                reinterpret_cast<unsigned long long*>(gcursor + rep8 * 256) + p;
            const unsigned long long add =
                (unsigned long long)cnt0 | ((unsigned long long)cnt1 << 32);
            const unsigned long long old = atomicAdd(g64, add);
            gbase[b0] = (uint32_t)old;
            gbase[b1] = (uint32_t)(old >> 32);
        }
    }
    // wave 0: in-register exclusive scan of counts -> lbase + cursor
    if (t < 64) {
        uint32_t v[4]; uint32_t s = 0;
        #pragma unroll
        for (int k = 0; k < 4; ++k) {
            const uint32_t tmp = hist[t * 4 + k];
            v[k] = s; s += tmp;
        }
        uint32_t inc = s;
        #pragma unroll
        for (int off = 1; off < 64; off <<= 1) {
            const uint32_t u = __shfl_up(inc, off, 64);
            if (t >= off) inc += u;
        }
        const uint32_t lane_excl = inc - s;
        #pragma unroll
        for (int k = 0; k < 4; ++k) {
            const uint32_t e = lane_excl + v[k];
            lbase[t * 4 + k]  = e;
            cursor[t * 4 + k] = e;
        }
    }
    __syncthreads();

    // rank-scatter into LDS stage (+ bucket id) — reserve atomics still in flight
    #pragma unroll
    for (int j = 0; j < EPT; ++j) {
        if (bk[j] >= 0) {
            const uint32_t r = atomicAdd(&cursor[bk[j]], 1u);
            stage[r]  = pk[j];
            stageb[r] = (unsigned char)bk[j];
        }
    }
    __syncthreads();   // stage, stageb, gbase all ready

    // linear full-occupancy copy-out: consecutive slots -> consecutive dst in-run
    for (int i = t; i < nval; i += THREADS) {
        const int b = (int)stageb[i];
        const uint32_t pos = gbase[b] + ((uint32_t)i - lbase[b]);
        if (pos < (uint32_t)REGr)            // overflow guard
            pairs[((size_t)b * NREP + rep8) * REGr + pos] = stage[i];
    }
}

// ---------------- K2: per-bucket accumulate -> out (replica per wave) ---------
__global__ __launch_bounds__(THREADS) void lj_accum_direct(
    const uint32_t* __restrict__ pairs,
    const uint32_t* __restrict__ gcursor,
    float* __restrict__ out,
    int REGr, int n_nodes)
{
    __shared__ float acc[NREP][BSIZE];       // 16KB, one replica per wave
    const int t = threadIdx.x;
    const int b = blockIdx.x;

    #pragma unroll
    for (int w = 0; w < NREP; ++w) acc[w][t] = 0.0f;
    __syncthreads();

    const int wave = t >> 6;                 // 0..7: one wave per replica chunk
    const int lane = t & 63;
    const uint32_t cnt = min(gcursor[wave * 256 + b], (uint32_t)REGr);
    const uint32_t* seg = pairs + ((size_t)b * NREP + wave) * REGr;
    for (uint32_t i = lane; i < cnt; i += 64) {
        const uint32_t p = seg[i];
        atomicAdd(&acc[wave][p & NMASK], __uint_as_float(p & ~NMASK));
    }
    __syncthreads();

    const long long n = (long long)b * BSIZE + t;
    if (n < n_nodes) {
        float s = 0.0f;
        #pragma unroll
        for (int w = 0; w < NREP; ++w) s += acc[w][t];
        out[n] = s;
    }
}

// ---------------- fallback: direct device-scope atomics -----------------------
__global__ __launch_bounds__(STHREADS) void lj_scatter_direct(
    const float* __restrict__ sigma,
    const float* __restrict__ delta,
    const float* __restrict__ epsilon,
    const float* __restrict__ edge_len,
    const float* __restrict__ edge_cutoff,
    const int*  __restrict__ edge_index,
    const int*  __restrict__ atom_types,
    float* __restrict__ out,
    int n_edges)
{
    __shared__ float s_sig[256], s_dlt[256], s_eps[256];
    const int t = threadIdx.x;
    load_params(sigma, delta, epsilon, s_sig, s_dlt, s_eps, t);
    __syncthreads();

    const int base = (blockIdx.x * STHREADS + t) * 4;
    if (base >= n_edges) return;
    const int lim = min(base + 4, n_edges);
    for (int e = base; e < lim; ++e) {
        const int ci = edge_index[e];
        const int oi = edge_index[n_edges + e];
        const int fl = (atom_types[ci] << 4) | atom_types[oi];
        const float en = lj_energy(s_sig[fl], s_dlt[fl], s_eps[fl],
                                   edge_len[e], edge_cutoff[e]);
        atomicAdd(out + ci, en);
    }
}

static inline size_t align16(size_t x) { return (x + 15) & ~(size_t)15; }

extern "C" void kernel_launch(void* const* d_in, const int* in_sizes, int n_in,
                              void* d_out, int out_size, void* d_ws, size_t ws_size,
                              hipStream_t stream) {
    const float* sigma       = (const float*)d_in[0];
    const float* delta       = (const float*)d_in[1];
    const float* epsilon     = (const float*)d_in[2];
    const float* edge_len    = (const float*)d_in[3];
    const float* edge_cutoff = (const float*)d_in[4];
    const int*   edge_index  = (const int*)d_in[5];
    const int*   atom_types  = (const int*)d_in[6];
    float*       out         = (float*)d_out;

    const int n_edges = in_sizes[3];
    const int n_nodes = in_sizes[6];

    const int nblk    = (n_edges + EPB - 1) / EPB;
    const int nbucket = (n_nodes + BSIZE - 1) / BSIZE;
    const int nwords  = (n_nodes + 7) >> 3;

    // per-(bucket,replica) sub-chunk: 2x mean, rounded to 512 (>=1024)
    int REGr = 2 * (n_edges / (nbucket > 0 ? nbucket * NREP : NREP));
    REGr = ((REGr + 511) / 512) * 512;
    if (REGr < 1024) REGr = 1024;

    const size_t gcur_bytes   = align16((size_t)NREP * 256 * sizeof(uint32_t));
    const size_t packed_bytes = align16((size_t)nwords * sizeof(uint32_t));
    const size_t pairs_bytes  = align16((size_t)nbucket * NREP * REGr * sizeof(uint32_t));
    const size_t need = gcur_bytes + packed_bytes + pairs_bytes;

    if (nbucket <= MAXB2 && nwords <= LDSWORDS && ws_size >= need) {
        char* p = (char*)d_ws;
        uint32_t* gcursor = (uint32_t*)p;  p += gcur_bytes;
        uint32_t* packed  = (uint32_t*)p;  p += packed_bytes;
        uint32_t* pairs   = (uint32_t*)p;

        const int pgrid = max((nwords + STHREADS - 1) / STHREADS, NREP);
        pack_types_kernel<<<pgrid, STHREADS, 0, stream>>>(
            atom_types, packed, gcursor, n_nodes);

        lj_fused<<<nblk, THREADS, 0, stream>>>(
            sigma, delta, epsilon, edge_len, edge_cutoff,
            edge_index, packed, gcursor, pairs, n_edges, n_nodes, nbucket, REGr);

        lj_accum_direct<<<nbucket, THREADS, 0, stream>>>(
            pairs, gcursor, out, REGr, n_nodes);
    } else {
        hipMemsetAsync(d_out, 0, (size_t)out_size * sizeof(float), stream);
        const int grid = (n_edges + STHREADS * 4 - 1) / (STHREADS * 4);
        lj_scatter_direct<<<grid, STHREADS, 0, stream>>>(
            sigma, delta, epsilon, edge_len, edge_cutoff,
            edge_index, atom_types, out, n_edges);
    }
}

// Round 21
// 51.995 us; speedup vs baseline: 5.7640x; 1.0337x over previous
//
#include <hip/hip_runtime.h>

// Lennard-Jones per-edge energy + segment-sum — fused binning, replicated cursors.
//
// R21 = R18/R20 structure with ONE change: lj_fused is a plain grid-stride
// kernel (grid = min(nchunk, 512) = 2 blocks/CU residency). Blocks stage the
// 50KB typeT nibble table ONCE and process 1-2 chunks (782 -> 512 stagings,
// tail becomes in-block loop). NO grid.sync (R19's poison), chunks independent.
//
// Pipeline: K0 pack nibbles+zero cursors -> K1 fused (grid-stride: energy+pack,
// LDS hist, wave-0 scan, off-path u64 region reserve, rank-scatter, linear
// copy-out to per-(bucket,replica) regions) -> K2 accum.
//
// Inputs: 0 sigma[16,16] 1 delta[16,16] 2 epsilon[16,16] (f32)
//         3 edge_len[E] 4 edge_cutoff[E] (f32)  5 edge_index[2,E] (int32)
//         6 atom_types[N] (int32)         Output: [N,1] f32.

#define THREADS  512
#define EPT      8
#define EPB      (THREADS*EPT)   // 4096
#define STHREADS 256
#define BSHIFT   9
#define BSIZE    512
#define MAXB2    256
#define NMASK    511u
#define LDSWORDS 12544
#define NREP     8               // cursor/region replica sets
#define MAXGRID  512             // 2 blocks/CU x 256 CU (76KB LDS caps at 2)

__device__ __forceinline__ float lj_energy(float sig, float dlt, float eps,
                                           float len, float cut) {
    const float r  = sig / (len - dlt);
    const float r2 = r * r;
    const float x  = r2 * r2 * r2;               // (sig/(len-dlt))^6
    return 2.0f * eps * (x * x - x) * cut;
}

__device__ __forceinline__ void load_params(const float* __restrict__ sigma,
                                            const float* __restrict__ delta,
                                            const float* __restrict__ epsilon,
                                            float* s_sig, float* s_dlt, float* s_eps,
                                            int t) {
    if (t < 256) {
        const int i  = t >> 4;
        const int j  = t & 15;
        const int lo = min(i, j);
        const int hi = max(i, j);
        const int src = lo * 16 + hi;        // sym = triu(p)+triu(p,1).T
        s_sig[t] = fmaxf(sigma[src],   0.0f);
        s_dlt[t] = fmaxf(delta[src],   0.0f);
        s_eps[t] = fmaxf(epsilon[src], 0.0f);
    }
}

// ---------------- K0: pack atom_types into nibbles + zero cursor replicas -----
__global__ __launch_bounds__(STHREADS) void pack_types_kernel(
    const int* __restrict__ at, uint32_t* __restrict__ packed,
    uint32_t* __restrict__ gcursor, int n_nodes)
{
    if (blockIdx.x < NREP)
        gcursor[blockIdx.x * 256 + threadIdx.x] = 0u;
    const int w = blockIdx.x * STHREADS + threadIdx.x;
    const int nwords = (n_nodes + 7) >> 3;
    if (w >= nwords) return;
    const int base = w * 8;
    uint32_t v = 0;
    if (base + 8 <= n_nodes) {
        const int4 a = *reinterpret_cast<const int4*>(at + base);
        const int4 b = *reinterpret_cast<const int4*>(at + base + 4);
        v =  (uint32_t)(a.x & 15)        | ((uint32_t)(a.y & 15) << 4)
          | ((uint32_t)(a.z & 15) << 8)  | ((uint32_t)(a.w & 15) << 12)
          | ((uint32_t)(b.x & 15) << 16) | ((uint32_t)(b.y & 15) << 20)
          | ((uint32_t)(b.z & 15) << 24) | ((uint32_t)(b.w & 15) << 28);
    } else {
        for (int k = 0; k < 8; ++k) {
            const int idx = base + k;
            const uint32_t tv = (idx < n_nodes) ? (uint32_t)(at[idx] & 15) : 0u;
            v |= tv << (4 * k);
        }
    }
    packed[w] = v;
}

// ---------------- K1: grid-stride fused energy + LDS sort + region scatter ----
__global__ __launch_bounds__(THREADS) void lj_fused(
    const float* __restrict__ sigma,
    const float* __restrict__ delta,
    const float* __restrict__ epsilon,
    const float* __restrict__ edge_len,
    const float* __restrict__ edge_cutoff,
    const int*  __restrict__ edge_index,     // [2,E]
    const uint32_t* __restrict__ packedT,    // [(n+7)/8]
    uint32_t* __restrict__ gcursor,          // [NREP][256] cursors
    uint32_t* __restrict__ pairs,            // [nbucket][NREP][REGr]
    int n_edges, int n_nodes, int nbucket, int nchunk, int REGr)
{
    __shared__ float s_sig[256], s_dlt[256], s_eps[256];
    __shared__ __align__(16) uint32_t typeT[LDSWORDS];  // 50KB nibble table
    __shared__ uint32_t hist[MAXB2];          // counts (NOT overwritten)
    __shared__ uint32_t cursor[MAXB2];        // rank cursors
    __shared__ uint32_t lbase[MAXB2];         // local exclusive base
    __shared__ uint32_t gbase[MAXB2];         // reserved global base
    __shared__ uint32_t stage[EPB];           // 16KB sorted stage
    __shared__ unsigned char stageb[EPB];     // 4KB bucket id per slot

    const int t = threadIdx.x;
    load_params(sigma, delta, epsilon, s_sig, s_dlt, s_eps, t);

    // stage nibble table into LDS ONCE per block
    const int nwords = (n_nodes + 7) >> 3;
    {
        const int nw4 = nwords >> 2;
        const uint4* s4 = reinterpret_cast<const uint4*>(packedT);
        uint4* d4 = reinterpret_cast<uint4*>(typeT);
        for (int i = t; i < nw4; i += THREADS) d4[i] = s4[i];
        for (int i = (nw4 << 2) + t; i < nwords; i += THREADS) typeT[i] = packedT[i];
    }

    #define TYPE_OF(idx) ((typeT[(idx) >> 3] >> (((idx) & 7) << 2)) & 15u)

    // grid-stride over edge chunks (independent; no inter-block sync needed)
    for (int chunk = blockIdx.x; chunk < nchunk; chunk += gridDim.x) {
        if (t < MAXB2) hist[t] = 0u;
        __syncthreads();   // typeT staged (1st iter) + hist cleared + prev copy-out done

        const int rep8    = chunk & (NREP - 1);
        const int blkbase = chunk * EPB;
        const int nval    = min(EPB, n_edges - blkbase);

        // 8 edges/thread: load + lookup + energy + pack + histogram
        uint32_t pk[EPT];
        int      bk[EPT];
        #pragma unroll
        for (int i = 0; i < EPT / 4; ++i) {
            const int g = blkbase + i * (THREADS * 4) + t * 4;
            if (g + 3 < n_edges) {
                const int4   ctr = *reinterpret_cast<const int4*>(edge_index + g);
                const int4   oth = *reinterpret_cast<const int4*>(edge_index + n_edges + g);
                const float4 len = *reinterpret_cast<const float4*>(edge_len + g);
                const float4 cut = *reinterpret_cast<const float4*>(edge_cutoff + g);
                const int   c[4] = {ctr.x, ctr.y, ctr.z, ctr.w};
                const int   o[4] = {oth.x, oth.y, oth.z, oth.w};
                const float L[4] = {len.x, len.y, len.z, len.w};
                const float C[4] = {cut.x, cut.y, cut.z, cut.w};
                #pragma unroll
                for (int k = 0; k < 4; ++k) {
                    const int fl = (int)((TYPE_OF(c[k]) << 4) | TYPE_OF(o[k]));
                    const float e = lj_energy(s_sig[fl], s_dlt[fl], s_eps[fl],
                                              L[k], C[k]);
                    pk[i*4+k] = (__float_as_uint(e) & ~NMASK) | (uint32_t)(c[k] & NMASK);
                    bk[i*4+k] = c[k] >> BSHIFT;
                    atomicAdd(&hist[bk[i*4+k]], 1u);
                }
            } else {
                #pragma unroll
                for (int k = 0; k < 4; ++k) {
                    const int e_idx = g + k;
                    if (e_idx < n_edges) {
                        const int ci = edge_index[e_idx];
                        const int oi = edge_index[n_edges + e_idx];
                        const int fl = (int)((TYPE_OF(ci) << 4) | TYPE_OF(oi));
                        const float e = lj_energy(s_sig[fl], s_dlt[fl], s_eps[fl],
                                                  edge_len[e_idx], edge_cutoff[e_idx]);
                        pk[i*4+k] = (__float_as_uint(e) & ~NMASK) | (uint32_t)(ci & NMASK);
                        bk[i*4+k] = ci >> BSHIFT;
                        atomicAdd(&hist[bk[i*4+k]], 1u);
                    } else {
                        bk[i*4+k] = -1;
                    }
                }
            }
        }
        __syncthreads();   // hist = final counts

        // waves 1-2: reserve region slots from COUNTS (off critical path)
        if (t >= 64 && t < 192) {
            const int p  = t - 64;
            const int b0 = 2 * p, b1 = 2 * p + 1;
            const uint32_t cnt0 = hist[b0];
            const uint32_t cnt1 = hist[b1];
            if ((cnt0 | cnt1) != 0u) {
                unsigned long long* g64 =
                    reinterpret_cast<unsigned long long*>(gcursor + rep8 * 256) + p;
                const unsigned long long add =
                    (unsigned long long)cnt0 | ((unsigned long long)cnt1 << 32);
                const unsigned long long old = atomicAdd(g64, add);
                gbase[b0] = (uint32_t)old;
                gbase[b1] = (uint32_t)(old >> 32);
            }
        }
        // wave 0: in-register exclusive scan of counts -> lbase + cursor
        if (t < 64) {
            uint32_t v[4]; uint32_t s = 0;
            #pragma unroll
            for (int k = 0; k < 4; ++k) {
                const uint32_t tmp = hist[t * 4 + k];
                v[k] = s; s += tmp;
            }
            uint32_t inc = s;
            #pragma unroll
            for (int off = 1; off < 64; off <<= 1) {
                const uint32_t u = __shfl_up(inc, off, 64);
                if (t >= off) inc += u;
            }
            const uint32_t lane_excl = inc - s;
            #pragma unroll
            for (int k = 0; k < 4; ++k) {
                const uint32_t e = lane_excl + v[k];
                lbase[t * 4 + k]  = e;
                cursor[t * 4 + k] = e;
            }
        }
        __syncthreads();

        // rank-scatter into LDS stage (+ bucket id)
        #pragma unroll
        for (int j = 0; j < EPT; ++j) {
            if (bk[j] >= 0) {
                const uint32_t r = atomicAdd(&cursor[bk[j]], 1u);
                stage[r]  = pk[j];
                stageb[r] = (unsigned char)bk[j];
            }
        }
        __syncthreads();   // stage, stageb, gbase all ready

        // linear full-occupancy copy-out
        for (int i = t; i < nval; i += THREADS) {
            const int b = (int)stageb[i];
            const uint32_t pos = gbase[b] + ((uint32_t)i - lbase[b]);
            if (pos < (uint32_t)REGr)        // overflow guard
                pairs[((size_t)b * NREP + rep8) * REGr + pos] = stage[i];
        }
        // loop-top __syncthreads (after hist clear) orders copy-out vs next front-end
    }
}

// ---------------- K2: per-bucket accumulate -> out (replica per wave) ---------
__global__ __launch_bounds__(THREADS) void lj_accum_direct(
    const uint32_t* __restrict__ pairs,
    const uint32_t* __restrict__ gcursor,
    float* __restrict__ out,
    int REGr, int n_nodes)
{
    __shared__ float acc[NREP][BSIZE];       // 16KB, one replica per wave
    const int t = threadIdx.x;
    const int b = blockIdx.x;

    #pragma unroll
    for (int w = 0; w < NREP; ++w) acc[w][t] = 0.0f;
    __syncthreads();

    const int wave = t >> 6;                 // 0..7: one wave per replica chunk
    const int lane = t & 63;
    const uint32_t cnt = min(gcursor[wave * 256 + b], (uint32_t)REGr);
    const uint32_t* seg = pairs + ((size_t)b * NREP + wave) * REGr;
    for (uint32_t i = lane; i < cnt; i += 64) {
        const uint32_t p = seg[i];
        atomicAdd(&acc[wave][p & NMASK], __uint_as_float(p & ~NMASK));
    }
    __syncthreads();

    const long long n = (long long)b * BSIZE + t;
    if (n < n_nodes) {
        float s = 0.0f;
        #pragma unroll
        for (int w = 0; w < NREP; ++w) s += acc[w][t];
        out[n] = s;
    }
}

// ---------------- fallback: direct device-scope atomics -----------------------
__global__ __launch_bounds__(STHREADS) void lj_scatter_direct(
    const float* __restrict__ sigma,
    const float* __restrict__ delta,
    const float* __restrict__ epsilon,
    const float* __restrict__ edge_len,
    const float* __restrict__ edge_cutoff,
    const int*  __restrict__ edge_index,
    const int*  __restrict__ atom_types,
    float* __restrict__ out,
    int n_edges)
{
    __shared__ float s_sig[256], s_dlt[256], s_eps[256];
    const int t = threadIdx.x;
    load_params(sigma, delta, epsilon, s_sig, s_dlt, s_eps, t);
    __syncthreads();

    const int base = (blockIdx.x * STHREADS + t) * 4;
    if (base >= n_edges) return;
    const int lim = min(base + 4, n_edges);
    for (int e = base; e < lim; ++e) {
        const int ci = edge_index[e];
        const int oi = edge_index[n_edges + e];
        const int fl = (atom_types[ci] << 4) | atom_types[oi];
        const float en = lj_energy(s_sig[fl], s_dlt[fl], s_eps[fl],
                                   edge_len[e], edge_cutoff[e]);
        atomicAdd(out + ci, en);
    }
}

static inline size_t align16(size_t x) { return (x + 15) & ~(size_t)15; }

extern "C" void kernel_launch(void* const* d_in, const int* in_sizes, int n_in,
                              void* d_out, int out_size, void* d_ws, size_t ws_size,
                              hipStream_t stream) {
    const float* sigma       = (const float*)d_in[0];
    const float* delta       = (const float*)d_in[1];
    const float* epsilon     = (const float*)d_in[2];
    const float* edge_len    = (const float*)d_in[3];
    const float* edge_cutoff = (const float*)d_in[4];
    const int*   edge_index  = (const int*)d_in[5];
    const int*   atom_types  = (const int*)d_in[6];
    float*       out         = (float*)d_out;

    const int n_edges = in_sizes[3];
    const int n_nodes = in_sizes[6];

    const int nchunk  = (n_edges + EPB - 1) / EPB;
    const int nbucket = (n_nodes + BSIZE - 1) / BSIZE;
    const int nwords  = (n_nodes + 7) >> 3;

    // per-(bucket,replica) sub-chunk: 2x mean, rounded to 512 (>=1024)
    int REGr = 2 * (n_edges / (nbucket > 0 ? nbucket * NREP : NREP));
    REGr = ((REGr + 511) / 512) * 512;
    if (REGr < 1024) REGr = 1024;

    const size_t gcur_bytes   = align16((size_t)NREP * 256 * sizeof(uint32_t));
    const size_t packed_bytes = align16((size_t)nwords * sizeof(uint32_t));
    const size_t pairs_bytes  = align16((size_t)nbucket * NREP * REGr * sizeof(uint32_t));
    const size_t need = gcur_bytes + packed_bytes + pairs_bytes;

    if (nbucket <= MAXB2 && nwords <= LDSWORDS && ws_size >= need) {
        char* p = (char*)d_ws;
        uint32_t* gcursor = (uint32_t*)p;  p += gcur_bytes;
        uint32_t* packed  = (uint32_t*)p;  p += packed_bytes;
        uint32_t* pairs   = (uint32_t*)p;

        const int pgrid = max((nwords + STHREADS - 1) / STHREADS, NREP);
        pack_types_kernel<<<pgrid, STHREADS, 0, stream>>>(
            atom_types, packed, gcursor, n_nodes);

        const int fgrid = min(nchunk, MAXGRID);
        lj_fused<<<fgrid, THREADS, 0, stream>>>(
            sigma, delta, epsilon, edge_len, edge_cutoff,
            edge_index, packed, gcursor, pairs,
            n_edges, n_nodes, nbucket, nchunk, REGr);

        lj_accum_direct<<<nbucket, THREADS, 0, stream>>>(
            pairs, gcursor, out, REGr, n_nodes);
    } else {
        hipMemsetAsync(d_out, 0, (size_t)out_size * sizeof(float), stream);
        const int grid = (n_edges + STHREADS * 4 - 1) / (STHREADS * 4);
        lj_scatter_direct<<<grid, STHREADS, 0, stream>>>(
            sigma, delta, epsilon, edge_len, edge_cutoff,
            edge_index, atom_types, out, n_edges);
    }
}